// Round 5
// baseline (131.224 us; speedup 1.0000x reference)
//
#include <hip/hip_runtime.h>

// BlockLinear: out[h*64+i][b] = sum_j W[h][i][j] * inp[h*64+j][b]
// H=16 blocks of 64x64 fp32, B=32768 columns.
// Round 5: lane = output row (D=64 = one wave). W row -> per-lane VGPRs
// (loop-invariant, static-indexed). x -> wave-uniform scalar loads (SGPRs).
// FMA = v_fmac(acc_v, w_v, x_s): 1 SGPR operand, float2-packed for pk_fma.
// acc = only 32 floats/thread -> no register-allocator fight.

constexpr int H = 16;
constexpr int D = 64;
constexpr int B = 32768;
constexpr int CPW = 32;              // columns per wave
constexpr int CPB = 4 * CPW;         // columns per block (4 waves)

__global__ __launch_bounds__(256)
void block_linear_kernel(const float* __restrict__ W,
                         const float* __restrict__ inp,
                         float* __restrict__ out)
{
    const int tid  = threadIdx.x;
    const int lane = tid & 63;                                  // output row i
    const int wv   = __builtin_amdgcn_readfirstlane(tid >> 6);  // wave id 0..3
    const int h    = blockIdx.y;
    const int colbase = blockIdx.x * CPB + wv * CPW;            // wave-uniform

    // Per-lane W row (lane = i): 64 loop-invariant floats in VGPRs.
    const float* wrow = W + ((size_t)h * D + lane) * D;
    float w[D];
    #pragma unroll
    for (int q = 0; q < D / 4; ++q) {
        float4 v = ((const float4*)wrow)[q];
        w[4 * q + 0] = v.x; w[4 * q + 1] = v.y;
        w[4 * q + 2] = v.z; w[4 * q + 3] = v.w;
    }

    const float* xb = inp + (size_t)h * D * B + colbase;        // wave-uniform

    float2 acc[CPW / 2];
    #pragma unroll
    for (int c = 0; c < CPW / 2; ++c) acc[c] = make_float2(0.f, 0.f);

    #pragma unroll
    for (int j = 0; j < D; ++j) {
        const float* xr = xb + (size_t)j * B;                   // wave-uniform
        #pragma unroll
        for (int c = 0; c < CPW / 2; ++c) {
            float2 xv = *(const float2*)(xr + 2 * c);           // scalar load
            acc[c].x = fmaf(w[j], xv.x, acc[c].x);
            acc[c].y = fmaf(w[j], xv.y, acc[c].y);
        }
    }

    // Lane writes its own contiguous 128 B row segment (fills full L2 lines).
    float* orow = out + ((size_t)h * D + lane) * B + colbase;
    #pragma unroll
    for (int q = 0; q < CPW / 4; ++q) {
        float4 v = make_float4(acc[2 * q].x, acc[2 * q].y,
                               acc[2 * q + 1].x, acc[2 * q + 1].y);
        ((float4*)orow)[q] = v;
    }
}

extern "C" void kernel_launch(void* const* d_in, const int* in_sizes, int n_in,
                              void* d_out, int out_size, void* d_ws, size_t ws_size,
                              hipStream_t stream) {
    const float* W   = (const float*)d_in[0];
    const float* inp = (const float*)d_in[1];
    float*       out = (float*)d_out;

    dim3 grid(B / CPB, H);   // 256 x 16 = 4096 workgroups
    block_linear_kernel<<<grid, dim3(256), 0, stream>>>(W, inp, out);
}

// Round 6
// 57.606 us; speedup vs baseline: 2.2780x; 2.2780x over previous
//
#include <hip/hip_runtime.h>
#include <hip/hip_bf16.h>

// BlockLinear: out[h*64+i][b] = sum_j W[h][i][j] * inp[h*64+j][b]
// H=16 blocks of 64x64 fp32, B=32768 columns.
// Round 6: MFMA bf16 path. No LDS, no barriers, no big VALU acc arrays.
// Per wave: M=64 x N=32 tile of one h; K=64 = 2 MFMA steps of 16x16x32.
// Fragment layout (m97-verified contiguous-k): lane l holds k = ks*32 + 8*(l>>4)+r.
// C/D: col = l&15, row = 4*(l>>4) + reg.

constexpr int H = 16;
constexpr int D = 64;
constexpr int B = 32768;

using bf16x8 = __attribute__((ext_vector_type(8))) short;
using f32x4  = __attribute__((ext_vector_type(4))) float;

__device__ inline unsigned pk2(float a, float b) {
    __hip_bfloat162 h2 = __float22bfloat162_rn(make_float2(a, b));
    union { __hip_bfloat162 h; unsigned u; } c;
    c.h = h2;
    return c.u;   // low 16 = a, high 16 = b
}

__global__ __launch_bounds__(256)
void block_linear_mfma(const float* __restrict__ W,
                       const float* __restrict__ inp,
                       float* __restrict__ out)
{
    const int tid = threadIdx.x;
    const int l   = tid & 63;
    const int wv  = __builtin_amdgcn_readfirstlane(tid >> 6);
    const int h   = blockIdx.y;
    const int wavecol = blockIdx.x * 128 + wv * 32;   // N=32 per wave

    const int l15 = l & 15;
    const int lk8 = (l >> 4) * 8;    // contiguous-8 k base per 16-lane group

    // ---- A fragments (W): afrag[mi][ks], lane holds
    // W[h][16*mi + l15][ks*32 + lk8 + 0..7] = 8 consecutive fp32.
    bf16x8 afrag[4][2];
    #pragma unroll
    for (int mi = 0; mi < 4; ++mi) {
        const float* wp = W + ((size_t)h * D + 16 * mi + l15) * D + lk8;
        #pragma unroll
        for (int ks = 0; ks < 2; ++ks) {
            float4 q0 = *(const float4*)(wp + ks * 32);
            float4 q1 = *(const float4*)(wp + ks * 32 + 4);
            union { bf16x8 v; unsigned u[4]; } f;
            f.u[0] = pk2(q0.x, q0.y);
            f.u[1] = pk2(q0.z, q0.w);
            f.u[2] = pk2(q1.x, q1.y);
            f.u[3] = pk2(q1.z, q1.w);
            afrag[mi][ks] = f.v;
        }
    }

    // ---- B fragments (X): bfrag[ni][ks], lane holds
    // X[h-rows: ks*32 + lk8 + r][wavecol + 16*ni + l15], r = 0..7 (8 strided dwords).
    const float* xb = inp + (size_t)h * D * B + wavecol + l15;
    bf16x8 bfrag[2][2];
    #pragma unroll
    for (int ni = 0; ni < 2; ++ni) {
        #pragma unroll
        for (int ks = 0; ks < 2; ++ks) {
            float e[8];
            #pragma unroll
            for (int r = 0; r < 8; ++r)
                e[r] = xb[(size_t)(ks * 32 + lk8 + r) * B + ni * 16];
            union { bf16x8 v; unsigned u[4]; } f;
            f.u[0] = pk2(e[0], e[1]);
            f.u[1] = pk2(e[2], e[3]);
            f.u[2] = pk2(e[4], e[5]);
            f.u[3] = pk2(e[6], e[7]);
            bfrag[ni][ks] = f.v;
        }
    }

    // ---- MFMA + store. acc frag (mi,ni): D[16mi + 4*(l>>4)+r][wavecol+16ni+l15]
    #pragma unroll
    for (int mi = 0; mi < 4; ++mi) {
        #pragma unroll
        for (int ni = 0; ni < 2; ++ni) {
            f32x4 c = {0.f, 0.f, 0.f, 0.f};
            c = __builtin_amdgcn_mfma_f32_16x16x32_bf16(afrag[mi][0], bfrag[ni][0], c, 0, 0, 0);
            c = __builtin_amdgcn_mfma_f32_16x16x32_bf16(afrag[mi][1], bfrag[ni][1], c, 0, 0, 0);

            const int row0 = 16 * mi + (l >> 4) * 4;
            float* ob = out + ((size_t)h * D + row0) * B + wavecol + 16 * ni + l15;
            #pragma unroll
            for (int r = 0; r < 4; ++r)
                ob[(size_t)r * B] = c[r];
        }
    }
}

extern "C" void kernel_launch(void* const* d_in, const int* in_sizes, int n_in,
                              void* d_out, int out_size, void* d_ws, size_t ws_size,
                              hipStream_t stream) {
    const float* W   = (const float*)d_in[0];
    const float* inp = (const float*)d_in[1];
    float*       out = (float*)d_out;

    dim3 grid(B / 128, H);   // 256 x 16 = 4096 workgroups; 128 cols per block
    block_linear_mfma<<<grid, dim3(256), 0, stream>>>(W, inp, out);
}

// Round 7
// 54.438 us; speedup vs baseline: 2.4105x; 1.0582x over previous
//
#include <hip/hip_runtime.h>
#include <hip/hip_bf16.h>

// BlockLinear: out[h*64+i][b] = sum_j W[h][i][j] * inp[h*64+j][b]
// Round 7: swapped-operand MFMA (A = X^T, B = W^T, D[b][i]) + persistent
// waves with a 2-deep column-tile pipeline.
//  - W frags are loop-invariant (loaded once/wave from L2).
//  - C/D layout gives 4 consecutive batch cols per lane -> float4 stores.
//  - Per tile: 32 independent dword X-loads issued a full tile ahead.
// Fragment layout (validated round 6): lane l holds k = ks*32 + 8*(l>>4)+r;
// C/D: row m = 4*(l>>4)+reg, col n = l&15.

constexpr int H   = 16;
constexpr int D   = 64;
constexpr int B   = 32768;
constexpr int NT  = 4;     // column-tiles per block
constexpr int TPB = 128;   // cols per tile per block (4 waves x 32)

using bf16x8 = __attribute__((ext_vector_type(8))) short;
using f32x4  = __attribute__((ext_vector_type(4))) float;

__device__ inline unsigned pk2(float a, float b) {
    __hip_bfloat162 h2 = __float22bfloat162_rn(make_float2(a, b));
    union { __hip_bfloat162 h; unsigned u; } c;
    c.h = h2;
    return c.u;   // low 16 = a, high 16 = b
}

__global__ __launch_bounds__(256)
void block_linear_mfma(const float* __restrict__ W,
                       const float* __restrict__ inp,
                       float* __restrict__ out)
{
    const int tid = threadIdx.x;
    const int l   = tid & 63;
    const int wv  = __builtin_amdgcn_readfirstlane(tid >> 6);
    const int h   = blockIdx.y;
    const int l15 = l & 15;
    const int lk8 = (l >> 4) * 8;
    const int lr4 = (l >> 4) * 4;

    // ---- B operand (W^T), loop-invariant: bfrag[ni][ks] holds
    // W[h][16*ni + l15][ks*32 + lk8 + 0..7] (8 consecutive fp32 -> 2 float4).
    bf16x8 bfrag[4][2];
    #pragma unroll
    for (int ni = 0; ni < 4; ++ni) {
        const float* wp = W + ((size_t)h * D + 16 * ni + l15) * D + lk8;
        #pragma unroll
        for (int ks = 0; ks < 2; ++ks) {
            float4 q0 = *(const float4*)(wp + ks * 32);
            float4 q1 = *(const float4*)(wp + ks * 32 + 4);
            union { bf16x8 v; unsigned u[4]; } f;
            f.u[0] = pk2(q0.x, q0.y);
            f.u[1] = pk2(q0.z, q0.w);
            f.u[2] = pk2(q1.x, q1.y);
            f.u[3] = pk2(q1.z, q1.w);
            bfrag[ni][ks] = f.v;
        }
    }

    // Wave's column base for tile t: blockbase + t*TPB + wv*32 (+16*mi + l15).
    const size_t blockbase = (size_t)blockIdx.x * (TPB * NT) + wv * 32;
    const float* xb = inp + (size_t)h * D * B + blockbase + l15;

    float xraw[2][2][2][8];   // [buf][mi][ks][r] — static indexing after unroll

    // Prologue: issue tile 0 loads.
    #pragma unroll
    for (int mi = 0; mi < 2; ++mi)
        #pragma unroll
        for (int ks = 0; ks < 2; ++ks)
            #pragma unroll
            for (int r = 0; r < 8; ++r)
                xraw[0][mi][ks][r] = xb[(size_t)(ks * 32 + lk8 + r) * B + 16 * mi];

    #pragma unroll
    for (int t = 0; t < NT; ++t) {
        // Issue next tile's loads before touching this tile's data.
        if (t + 1 < NT) {
            const float* xt = xb + (size_t)(t + 1) * TPB;
            #pragma unroll
            for (int mi = 0; mi < 2; ++mi)
                #pragma unroll
                for (int ks = 0; ks < 2; ++ks)
                    #pragma unroll
                    for (int r = 0; r < 8; ++r)
                        xraw[(t + 1) & 1][mi][ks][r] =
                            xt[(size_t)(ks * 32 + lk8 + r) * B + 16 * mi];
        }

        // Convert tile t to A fragments (waits only on tile t's loads).
        bf16x8 a[2][2];
        #pragma unroll
        for (int mi = 0; mi < 2; ++mi)
            #pragma unroll
            for (int ks = 0; ks < 2; ++ks) {
                const float* e = xraw[t & 1][mi][ks];
                union { bf16x8 v; unsigned u[4]; } f;
                f.u[0] = pk2(e[0], e[1]);
                f.u[1] = pk2(e[2], e[3]);
                f.u[2] = pk2(e[4], e[5]);
                f.u[3] = pk2(e[6], e[7]);
                a[mi][ks] = f.v;
            }

        // D[b][i]: 16 MFMAs, acc in the unified ACC file (static f32x4).
        f32x4 acc[2][4];
        #pragma unroll
        for (int mi = 0; mi < 2; ++mi)
            #pragma unroll
            for (int ni = 0; ni < 4; ++ni) {
                f32x4 c = {0.f, 0.f, 0.f, 0.f};
                c = __builtin_amdgcn_mfma_f32_16x16x32_bf16(a[mi][0], bfrag[ni][0], c, 0, 0, 0);
                c = __builtin_amdgcn_mfma_f32_16x16x32_bf16(a[mi][1], bfrag[ni][1], c, 0, 0, 0);
                acc[mi][ni] = c;
            }

        // Stores: lane's 4 acc values are 4 consecutive batch cols -> float4.
        const size_t b0 = blockbase + (size_t)t * TPB + lr4;
        #pragma unroll
        for (int mi = 0; mi < 2; ++mi)
            #pragma unroll
            for (int ni = 0; ni < 4; ++ni) {
                float* op = out + ((size_t)h * D + 16 * ni + l15) * B + b0 + 16 * mi;
                f32x4 c = acc[mi][ni];
                float4 v = make_float4(c[0], c[1], c[2], c[3]);
                *(float4*)op = v;
            }
    }
}

extern "C" void kernel_launch(void* const* d_in, const int* in_sizes, int n_in,
                              void* d_out, int out_size, void* d_ws, size_t ws_size,
                              hipStream_t stream) {
    const float* W   = (const float*)d_in[0];
    const float* inp = (const float*)d_in[1];
    float*       out = (float*)d_out;

    dim3 grid(B / (TPB * NT), H);   // 64 x 16 = 1024 persistent blocks
    block_linear_mfma<<<grid, dim3(256), 0, stream>>>(W, inp, out);
}